// Round 11
// baseline (25.116 us; speedup 1.0000x reference)
//
#include <hip/hip_runtime.h>
#include <hip/hip_bf16.h>
#include <math.h>

#define NB 4096
#define NC 512
#define NF 128
#define NK 256           // GEMM K = 2*F  (k<128: xn^2 . iv ; k>=128: xn . -2*mu*iv)
#define TAUc 32.0f
#define ALPHAc 0.9f

typedef __attribute__((ext_vector_type(8))) short bf16x8;
typedef __attribute__((ext_vector_type(4))) float f32x4;

// Truncation-based bf16 hi/lo split: hi = trunc16(x), lo = trunc16(x - hi).
__device__ inline void splitbf(float x, short& hi, short& lo) {
  unsigned u = __float_as_uint(x);
  hi = (short)(u >> 16);
  float l = x - __uint_as_float(u & 0xFFFF0000u);
  lo = (short)(__float_as_uint(l) >> 16);
}

// ---------- fallback-only mask machinery (not launched when Csel==NC) ------------
__global__ __launch_bounds__(512) void k_zero(int* __restrict__ colnz) {
  colnz[threadIdx.x] = 0;
}

__global__ __launch_bounds__(256) void k_mask(const int* __restrict__ T,
                                              int* __restrict__ colnz) {
  int r0 = blockIdx.x * 16;
  int a0 = 0, a1 = 0;
  for (int r = 0; r < 16; ++r) {
    const int* row = T + (size_t)(r0 + r) * NC;
    a0 |= row[threadIdx.x];
    a1 |= row[threadIdx.x + 256];
  }
  if (a0) atomicOr(colnz + threadIdx.x, 1);
  if (a1) atomicOr(colnz + threadIdx.x + 256, 1);
}

__global__ __launch_bounds__(512) void k_scan(const int* __restrict__ colnz,
                                              int* __restrict__ pos) {
  __shared__ int s[NC];
  int t = threadIdx.x;
  int f = colnz[t] ? 1 : 0;
  s[t] = f;
  __syncthreads();
  for (int o = 1; o < NC; o <<= 1) {
    int add = (t >= o) ? s[t - o] : 0;
    __syncthreads();
    s[t] += add;
    __syncthreads();
  }
  pos[t] = s[t] - f;
}

// ---------- fused v11: 64 rows x 64 cols per block, 2 blocks/CU ------------------
// grid = 64 row-groups x 8 col-groups = 512 blocks, 256 threads = 4 waves.
// LDS = 64.3 KB (B hi/lo + t3) -> TWO blocks co-resident per CU: independent
// barrier domains overlap staging latency of one block with MFMA/epilogue of the
// other. Per-CU arithmetic identical to v10; only the serialization changes.
// Wave w owns rows [w*16,+16) x all 64 cols. Rows wave-private -> single barrier,
// softmax from accumulators, partials published straight to ws (no LDS combine).
__global__ __launch_bounds__(256) void k_fused(const float* __restrict__ X,
                                               const int* __restrict__ T,
                                               const float* __restrict__ means,
                                               const float* __restrict__ logv,
                                               const int* __restrict__ colnz,
                                               const int* __restrict__ pos,
                                               float* __restrict__ Sout,
                                               float* __restrict__ rowm,
                                               float* __restrict__ rowz,
                                               float* __restrict__ rowp,
                                               int Csel, int ident) {
  __shared__ __align__(16) unsigned char smB[65536];   // Bh @0 (32K), Bl @32K
  __shared__ float t3s[64];
  int tid = threadIdx.x;
  int lane = tid & 63, w = tid >> 6;        // w = 0..3
  int lr = lane & 15, kq = lane >> 4;
  int bx = blockIdx.x;
  int gc = bx & 7, gr = bx >> 3;            // col-group ~ XCD under round-robin
  int r0 = gr * 64, c0 = gc * 64;

  // ---- B-build ownership: class cls (block-local col), f in [32q, 32q+32) ----
  int cls = w * 16 + (lane >> 2);           // 0..63 ; ct = w, lr2 = lane>>2
  int q = lane & 3;
  int lr2 = lane >> 2;
  float mua[32], lva[32];
  {
    const float4* mp = (const float4*)(means + (size_t)(c0 + cls) * NF + 32 * q);
    const float4* lp = (const float4*)(logv + (size_t)(c0 + cls) * NF + 32 * q);
    #pragma unroll
    for (int i = 0; i < 8; ++i) {
      *(float4*)(mua + 4 * i) = mp[i];
      *(float4*)(lva + 4 * i) = lp[i];
    }
  }

  // ---- A-input loads (independent; overlap B compute) ----
  float xv[4][8];
  {
    const float* xrow = X + (size_t)(r0 + w * 16 + lr) * NF + 8 * kq;
    #pragma unroll
    for (int c = 0; c < 4; ++c) {
      float4 u0 = *(const float4*)(xrow + 32 * c);
      float4 u1 = *(const float4*)(xrow + 32 * c + 4);
      xv[c][0] = u0.x; xv[c][1] = u0.y; xv[c][2] = u0.z; xv[c][3] = u0.w;
      xv[c][4] = u1.x; xv[c][5] = u1.y; xv[c][6] = u1.z; xv[c][7] = u1.w;
    }
  }
  // ---- T patch prefetch (rows w*16+4kq+i, cols c0+16t+lr) ----
  int tfv[4][4];
  #pragma unroll
  for (int i = 0; i < 4; ++i) {
    const int* tr = T + (size_t)(r0 + w * 16 + 4 * kq + i) * NC + c0 + lr;
    #pragma unroll
    for (int t = 0; t < 4; ++t) tfv[t][i] = tr[16 * t];
  }

  // ---- B compute: class norm (4-lane reduce), split, fragment-order LDS write --
  {
    float s = 0.f;
    #pragma unroll
    for (int k = 0; k < 32; ++k) s = fmaf(mua[k], mua[k], s);
    s += __shfl_xor(s, 1, 64);
    s += __shfl_xor(s, 2, 64);
    float rn_c = 1.0f / fmaxf(sqrtf(s), 1e-12f);
    float t3a = 0.f;
    #pragma unroll
    for (int kq2 = 0; kq2 < 4; ++kq2) {
      bf16x8 h1, l1, h2, l2;
      #pragma unroll
      for (int j = 0; j < 8; ++j) {
        int jj = kq2 * 8 + j;
        float ivv = __expf(-fminf(fmaxf(lva[jj], 0.f), 6.f));
        float m = mua[jj] * rn_c;
        short h, l;
        splitbf(ivv, h, l);
        h1[j] = h; l1[j] = l;
        splitbf(-2.f * m * ivv, h, l);
        h2[j] = h; l2[j] = l;
        t3a = fmaf(m * m, ivv, t3a);
      }
      // b1 at k8=q, b2 at k8=4+q; byte = ((ct*8+k8)*64 + kq2*16 + lr2)*16, ct=w
      unsigned e1 = (unsigned)(((w * 8 + q) * 64 + kq2 * 16 + lr2) * 16);
      unsigned e2 = (unsigned)(((w * 8 + 4 + q) * 64 + kq2 * 16 + lr2) * 16);
      *(bf16x8*)(smB + e1) = h1;
      *(bf16x8*)(smB + 32768 + e1) = l1;
      *(bf16x8*)(smB + e2) = h2;
      *(bf16x8*)(smB + 32768 + e2) = l2;
    }
    t3a += __shfl_xor(t3a, 1, 64);
    t3a += __shfl_xor(t3a, 2, 64);
    if (q == 0) t3s[cls] = t3a;
  }

  // ---- A-build (X already in regs) ----
  bf16x8 Afh[8], Afl[8];
  {
    float rsum = 0.f;
    #pragma unroll
    for (int c = 0; c < 4; ++c)
      #pragma unroll
      for (int j = 0; j < 8; ++j) rsum = fmaf(xv[c][j], xv[c][j], rsum);
    rsum += __shfl_xor(rsum, 16, 64);
    rsum += __shfl_xor(rsum, 32, 64);
    float rn = 1.0f / fmaxf(sqrtf(rsum), 1e-12f);
    #pragma unroll
    for (int c = 0; c < 4; ++c) {
      #pragma unroll
      for (int j = 0; j < 8; ++j) {
        float xn = xv[c][j] * rn;
        short h, l;
        splitbf(xn * xn, h, l);
        Afh[c][j] = h; Afl[c][j] = l;
        splitbf(xn, h, l);
        Afh[c + 4][j] = h; Afl[c + 4][j] = l;
      }
    }
  }

  __syncthreads();   // B slice + t3 resident (single barrier in the kernel)

  // ---- MFMA: 3-product split-bf16; B frags from shared LDS ----
  f32x4 acc[4] = {};
  #pragma unroll
  for (int k8 = 0; k8 < 8; ++k8) {
    #pragma unroll
    for (int t = 0; t < 4; ++t) {
      unsigned off = (unsigned)(((t * 8 + k8) * 64 + lane) * 16);
      bf16x8 bh = *(const bf16x8*)(smB + off);
      bf16x8 bl = *(const bf16x8*)(smB + 32768 + off);
      acc[t] = __builtin_amdgcn_mfma_f32_16x16x32_bf16(Afh[k8], bh, acc[t], 0, 0, 0);
      acc[t] = __builtin_amdgcn_mfma_f32_16x16x32_bf16(Afl[k8], bh, acc[t], 0, 0, 0);
      acc[t] = __builtin_amdgcn_mfma_f32_16x16x32_bf16(Afh[k8], bl, acc[t], 0, 0, 0);
    }
  }

  // ---- D in registers: d[t][i] = acc + t3 ; C/D layout col=lr, row=4*kq+i ----
  float d[4][4];
  #pragma unroll
  for (int t = 0; t < 4; ++t) {
    float tt = t3s[16 * t + lr];
    #pragma unroll
    for (int i = 0; i < 4; ++i) d[t][i] = acc[t][i] + tt;
  }

  // ---- partial softmax over this block's 64 cols (wave-private rows) ----
  float m4[4], Zi[4], Pi[4];
  #pragma unroll
  for (int i = 0; i < 4; ++i) {
    float mm = fminf(fminf(d[0][i], d[1][i]), fminf(d[2][i], d[3][i]));
    #pragma unroll
    for (int o = 1; o < 16; o <<= 1) mm = fminf(mm, __shfl_xor(mm, o, 64));
    float Z = 0.f, P = 0.f;
    #pragma unroll
    for (int t = 0; t < 4; ++t) {
      float p = __expf(TAUc * (mm - d[t][i]));
      Z += p;
      if (tfv[t][i]) P += p;
    }
    #pragma unroll
    for (int o = 1; o < 16; o <<= 1) { Z += __shfl_xor(Z, o, 64); P += __shfl_xor(P, o, 64); }
    m4[i] = mm; Zi[i] = Z; Pi[i] = P;
  }

  // ---- S patch (column-local) ----
  if (ident) {
    #pragma unroll
    for (int i = 0; i < 4; ++i) {
      float* srow = Sout + (size_t)(r0 + w * 16 + 4 * kq + i) * NC + c0 + lr;
      #pragma unroll
      for (int t = 0; t < 4; ++t)
        srow[16 * t] = tfv[t][i] ? 1.0f : __expf(-ALPHAc * d[t][i]);
    }
  } else {
    #pragma unroll
    for (int i = 0; i < 4; ++i) {
      float* srow = Sout + (size_t)(r0 + w * 16 + 4 * kq + i) * Csel;
      #pragma unroll
      for (int t = 0; t < 4; ++t) {
        int c = c0 + 16 * t + lr;
        if (colnz[c]) srow[pos[c]] = tfv[t][i] ? 1.0f : __expf(-ALPHAc * d[t][i]);
      }
    }
  }

  // ---- publish per-(row, col-group) partials (no LDS combine needed) ----
  if (lr == 0) {
    #pragma unroll
    for (int i = 0; i < 4; ++i) {
      int g = (r0 + w * 16 + 4 * kq + i) * 8 + gc;
      rowm[g] = m4[i];
      rowz[g] = Zi[i];
      rowp[g] = Pi[i];
    }
  }
}

// ---------- fin: combine 8 col-group partials per row -> loss --------------------
__global__ __launch_bounds__(1024) void k_fin(const float* __restrict__ rowm,
                                              const float* __restrict__ rowz,
                                              const float* __restrict__ rowp,
                                              float* __restrict__ out) {
  __shared__ float sl[16];
  __shared__ int sc[16];
  int tid = threadIdx.x;
  int lane = tid & 63, w = tid >> 6;
  float ls = 0.f; int lc = 0;
  for (int r = tid; r < NB; r += 1024) {
    float4 m0 = ((const float4*)rowm)[2 * r];
    float4 m1 = ((const float4*)rowm)[2 * r + 1];
    float4 z0 = ((const float4*)rowz)[2 * r];
    float4 z1 = ((const float4*)rowz)[2 * r + 1];
    float4 p0 = ((const float4*)rowp)[2 * r];
    float4 p1 = ((const float4*)rowp)[2 * r + 1];
    float m = fminf(fminf(fminf(m0.x, m0.y), fminf(m0.z, m0.w)),
                    fminf(fminf(m1.x, m1.y), fminf(m1.z, m1.w)));
    float Z = 0.f, P = 0.f;
    {
      float e;
      e = __expf(TAUc * (m - m0.x)); Z += z0.x * e; P += p0.x * e;
      e = __expf(TAUc * (m - m0.y)); Z += z0.y * e; P += p0.y * e;
      e = __expf(TAUc * (m - m0.z)); Z += z0.z * e; P += p0.z * e;
      e = __expf(TAUc * (m - m0.w)); Z += z0.w * e; P += p0.w * e;
      e = __expf(TAUc * (m - m1.x)); Z += z1.x * e; P += p1.x * e;
      e = __expf(TAUc * (m - m1.y)); Z += z1.y * e; P += p1.y * e;
      e = __expf(TAUc * (m - m1.z)); Z += z1.z * e; P += p1.z * e;
      e = __expf(TAUc * (m - m1.w)); Z += z1.w * e; P += p1.w * e;
    }
    float Ps = P / Z;
    if (Ps > 0.f) { ls += logf(Ps); ++lc; }
  }
  #pragma unroll
  for (int o = 1; o < 64; o <<= 1) { ls += __shfl_xor(ls, o, 64); lc += __shfl_xor(lc, o, 64); }
  if (lane == 0) { sl[w] = ls; sc[w] = lc; }
  __syncthreads();
  if (tid == 0) {
    float s = 0.f; int c = 0;
    #pragma unroll
    for (int i = 0; i < 16; ++i) { s += sl[i]; c += sc[i]; }
    out[0] = -s / fmaxf((float)c, 1.0f);
  }
}

extern "C" void kernel_launch(void* const* d_in, const int* in_sizes, int n_in,
                              void* d_out, int out_size, void* d_ws, size_t ws_size,
                              hipStream_t stream) {
  const float* X     = (const float*)d_in[0];
  const int*   T     = (const int*)d_in[1];
  const float* means = (const float*)d_in[2];
  const float* logv  = (const float*)d_in[3];
  float* out = (float*)d_out;
  char* ws = (char*)d_ws;

  float*  rowm = (float*) (ws);                  // 128 KB  [4096][8]
  float*  rowz = (float*) (ws + 131072);         // 128 KB
  float*  rowp = (float*) (ws + 262144);         // 128 KB
  int*    colnz= (int*)   (ws + 393216);         // 2 KB
  int*    pos  = (int*)   (ws + 395264);         // 2 KB

  int Csel = (out_size - 1) / NB;
  int ident = (Csel == NC);   // Csel==NC forces all-ones mask (pos = identity)

  if (!ident) {
    k_zero<<<1, NC, 0, stream>>>(colnz);
    k_mask<<<NB / 16, 256, 0, stream>>>(T, colnz);
    k_scan<<<1, NC, 0, stream>>>(colnz, pos);
  }
  k_fused<<<512, 256, 0, stream>>>(X, T, means, logv, colnz, pos,
                                   out + 1, rowm, rowz, rowp, Csel, ident);
  k_fin<<<1, 1024, 0, stream>>>(rowm, rowz, rowp, out);
}

// Round 12
// 22.197 us; speedup vs baseline: 1.1315x; 1.1315x over previous
//
#include <hip/hip_runtime.h>
#include <hip/hip_bf16.h>
#include <math.h>

#define NB 4096
#define NC 512
#define NF 128
#define NK 256           // GEMM K = 2*F  (k<128: xn^2 . iv ; k>=128: xn . -2*mu*iv)
#define TAUc 32.0f
#define ALPHAc 0.9f

typedef __attribute__((ext_vector_type(8))) short bf16x8;
typedef __attribute__((ext_vector_type(4))) float f32x4;

// Truncation-based bf16 hi/lo split: hi = trunc16(x), lo = trunc16(x - hi).
__device__ inline void splitbf(float x, short& hi, short& lo) {
  unsigned u = __float_as_uint(x);
  hi = (short)(u >> 16);
  float l = x - __uint_as_float(u & 0xFFFF0000u);
  lo = (short)(__float_as_uint(l) >> 16);
}

// ---------- fallback-only mask machinery (not launched when Csel==NC) ------------
__global__ __launch_bounds__(512) void k_zero(int* __restrict__ colnz) {
  colnz[threadIdx.x] = 0;
}

__global__ __launch_bounds__(256) void k_mask(const int* __restrict__ T,
                                              int* __restrict__ colnz) {
  int r0 = blockIdx.x * 16;
  int a0 = 0, a1 = 0;
  for (int r = 0; r < 16; ++r) {
    const int* row = T + (size_t)(r0 + r) * NC;
    a0 |= row[threadIdx.x];
    a1 |= row[threadIdx.x + 256];
  }
  if (a0) atomicOr(colnz + threadIdx.x, 1);
  if (a1) atomicOr(colnz + threadIdx.x + 256, 1);
}

__global__ __launch_bounds__(512) void k_scan(const int* __restrict__ colnz,
                                              int* __restrict__ pos) {
  __shared__ int s[NC];
  int t = threadIdx.x;
  int f = colnz[t] ? 1 : 0;
  s[t] = f;
  __syncthreads();
  for (int o = 1; o < NC; o <<= 1) {
    int add = (t >= o) ? s[t - o] : 0;
    __syncthreads();
    s[t] += add;
    __syncthreads();
  }
  pos[t] = s[t] - f;
}

// ---------- fused v10 (best measured): in-block B build + GEMM + softmax + S -----
// grid = 64 row-groups x 4 col-groups = 256 blocks, 512 threads = 8 waves.
// Phase A: thread (class = block-local col, quarter q) computes mu_n/iv/t3,
//   trunc-splits, ds_write_b128 straight into LDS in MFMA fragment order.
// Phase B: A in registers, 3-product split-bf16 MFMA, rows wave-private ->
//   softmax from accumulators, partial (m,Z,P) per (row, col-group) published.
__global__ __launch_bounds__(512) void k_fused(const float* __restrict__ X,
                                               const int* __restrict__ T,
                                               const float* __restrict__ means,
                                               const float* __restrict__ logv,
                                               const int* __restrict__ colnz,
                                               const int* __restrict__ pos,
                                               float* __restrict__ Sout,
                                               float* __restrict__ rowm,
                                               float* __restrict__ rowz,
                                               float* __restrict__ rowp,
                                               int Csel, int ident) {
  __shared__ __align__(16) unsigned char smB[131072];   // Bh slice @0, Bl @64K
  __shared__ float t3s[128];
  __shared__ float partm[2][64], partz[2][64], partp[2][64];
  int tid = threadIdx.x;
  int lane = tid & 63, w = tid >> 6;
  int wm = w & 3, wn = w >> 2;
  int lr = lane & 15, kq = lane >> 4;
  int bx = blockIdx.x;
  int gc = bx & 3, gr = bx >> 2;
  int r0 = gr * 64, c0 = gc * 128;

  // ---- B-build: this thread owns class cls, f in [32q, 32q+32) ----
  int cls = w * 16 + (lane >> 2);        // block-local class 0..127
  int q = lane & 3;
  int c15 = (lane >> 2) & 15;
  float mua[32], lva[32];
  {
    const float4* mp = (const float4*)(means + (size_t)(c0 + cls) * NF + 32 * q);
    const float4* lp = (const float4*)(logv + (size_t)(c0 + cls) * NF + 32 * q);
    #pragma unroll
    for (int i = 0; i < 8; ++i) {
      *(float4*)(mua + 4 * i) = mp[i];
      *(float4*)(lva + 4 * i) = lp[i];
    }
  }

  // ---- A-input loads issue here (independent; overlap B compute) ----
  float xv[4][8];
  {
    const float* xrow = X + (size_t)(r0 + wm * 16 + lr) * NF + 8 * kq;
    #pragma unroll
    for (int c = 0; c < 4; ++c) {
      float4 u0 = *(const float4*)(xrow + 32 * c);
      float4 u1 = *(const float4*)(xrow + 32 * c + 4);
      xv[c][0] = u0.x; xv[c][1] = u0.y; xv[c][2] = u0.z; xv[c][3] = u0.w;
      xv[c][4] = u1.x; xv[c][5] = u1.y; xv[c][6] = u1.z; xv[c][7] = u1.w;
    }
  }
  // ---- T patch prefetch ----
  int tfv[4][4];
  #pragma unroll
  for (int i = 0; i < 4; ++i) {
    const int* tr = T + (size_t)(r0 + wm * 16 + 4 * kq + i) * NC + c0 + wn * 64 + lr;
    #pragma unroll
    for (int t = 0; t < 4; ++t) tfv[t][i] = tr[16 * t];
  }

  // ---- B compute: class norm (4-lane reduce), split, fragment-order LDS write --
  {
    float s = 0.f;
    #pragma unroll
    for (int k = 0; k < 32; ++k) s = fmaf(mua[k], mua[k], s);
    s += __shfl_xor(s, 1, 64);
    s += __shfl_xor(s, 2, 64);
    float rn_c = 1.0f / fmaxf(sqrtf(s), 1e-12f);
    float t3a = 0.f;
    #pragma unroll
    for (int i8 = 0; i8 < 4; ++i8) {
      bf16x8 h1, l1, h2, l2;
      #pragma unroll
      for (int j = 0; j < 8; ++j) {
        int jj = i8 * 8 + j;
        float ivv = __expf(-fminf(fmaxf(lva[jj], 0.f), 6.f));
        float m = mua[jj] * rn_c;
        short h, l;
        splitbf(ivv, h, l);
        h1[j] = h; l1[j] = l;
        splitbf(-2.f * m * ivv, h, l);
        h2[j] = h; l2[j] = l;
        t3a = fmaf(m * m, ivv, t3a);
      }
      // b1 at k5=q, b2 at k5=4+q; elem addr = (w*8+k5)*512 + i8*128 + c15*8
      unsigned e1 = (unsigned)((w * 8 + q) * 512 + i8 * 128 + c15 * 8) * 2u;
      unsigned e2 = (unsigned)((w * 8 + 4 + q) * 512 + i8 * 128 + c15 * 8) * 2u;
      *(bf16x8*)(smB + e1) = h1;
      *(bf16x8*)(smB + 65536 + e1) = l1;
      *(bf16x8*)(smB + e2) = h2;
      *(bf16x8*)(smB + 65536 + e2) = l2;
    }
    t3a += __shfl_xor(t3a, 1, 64);
    t3a += __shfl_xor(t3a, 2, 64);
    if (q == 0) t3s[cls] = t3a;
  }

  // ---- A-build (X already in regs) ----
  bf16x8 Afh[8], Afl[8];
  {
    float rsum = 0.f;
    #pragma unroll
    for (int c = 0; c < 4; ++c)
      #pragma unroll
      for (int j = 0; j < 8; ++j) rsum = fmaf(xv[c][j], xv[c][j], rsum);
    rsum += __shfl_xor(rsum, 16, 64);
    rsum += __shfl_xor(rsum, 32, 64);
    float rn = 1.0f / fmaxf(sqrtf(rsum), 1e-12f);
    #pragma unroll
    for (int c = 0; c < 4; ++c) {
      #pragma unroll
      for (int j = 0; j < 8; ++j) {
        float xn = xv[c][j] * rn;
        short h, l;
        splitbf(xn * xn, h, l);
        Afh[c][j] = h; Afl[c][j] = l;
        splitbf(xn, h, l);
        Afh[c + 4][j] = h; Afl[c + 4][j] = l;
      }
    }
  }

  __syncthreads();   // B slice + t3 resident in LDS

  // ---- MFMA: 3-product split-bf16; B frags from shared LDS ----
  f32x4 acc[4] = {};
  #pragma unroll
  for (int k8 = 0; k8 < 8; ++k8) {
    #pragma unroll
    for (int t = 0; t < 4; ++t) {
      unsigned off = (unsigned)((((wn * 4 + t) * 8 + k8) * 64 + lane) * 16);
      bf16x8 bh = *(const bf16x8*)(smB + off);
      bf16x8 bl = *(const bf16x8*)(smB + 65536 + off);
      acc[t] = __builtin_amdgcn_mfma_f32_16x16x32_bf16(Afh[k8], bh, acc[t], 0, 0, 0);
      acc[t] = __builtin_amdgcn_mfma_f32_16x16x32_bf16(Afl[k8], bh, acc[t], 0, 0, 0);
      acc[t] = __builtin_amdgcn_mfma_f32_16x16x32_bf16(Afh[k8], bl, acc[t], 0, 0, 0);
    }
  }

  // ---- D in registers: d[t][i] = acc + t3 ; C/D layout col=lr, row=4*kq+i ----
  float d[4][4];
  #pragma unroll
  for (int t = 0; t < 4; ++t) {
    float tt = t3s[wn * 64 + 16 * t + lr];
    #pragma unroll
    for (int i = 0; i < 4; ++i) d[t][i] = acc[t][i] + tt;
  }

  // ---- partial softmax over this wave's 64 cols ----
  float m4[4], Zi[4], Pi[4];
  #pragma unroll
  for (int i = 0; i < 4; ++i) {
    float mm = fminf(fminf(d[0][i], d[1][i]), fminf(d[2][i], d[3][i]));
    #pragma unroll
    for (int o = 1; o < 16; o <<= 1) mm = fminf(mm, __shfl_xor(mm, o, 64));
    float Z = 0.f, P = 0.f;
    #pragma unroll
    for (int t = 0; t < 4; ++t) {
      float p = __expf(TAUc * (mm - d[t][i]));
      Z += p;
      if (tfv[t][i]) P += p;
    }
    #pragma unroll
    for (int o = 1; o < 16; o <<= 1) { Z += __shfl_xor(Z, o, 64); P += __shfl_xor(P, o, 64); }
    m4[i] = mm; Zi[i] = Z; Pi[i] = P;
  }

  // ---- S patch (column-local) ----
  if (ident) {
    #pragma unroll
    for (int i = 0; i < 4; ++i) {
      float* srow = Sout + (size_t)(r0 + wm * 16 + 4 * kq + i) * NC + c0 + wn * 64 + lr;
      #pragma unroll
      for (int t = 0; t < 4; ++t)
        srow[16 * t] = tfv[t][i] ? 1.0f : __expf(-ALPHAc * d[t][i]);
    }
  } else {
    #pragma unroll
    for (int i = 0; i < 4; ++i) {
      float* srow = Sout + (size_t)(r0 + wm * 16 + 4 * kq + i) * Csel;
      #pragma unroll
      for (int t = 0; t < 4; ++t) {
        int c = c0 + wn * 64 + 16 * t + lr;
        if (colnz[c]) srow[pos[c]] = tfv[t][i] ? 1.0f : __expf(-ALPHAc * d[t][i]);
      }
    }
  }

  // ---- combine wn-halves in LDS, publish per-(row, col-group) partials ----
  if (lr == 0) {
    #pragma unroll
    for (int i = 0; i < 4; ++i) {
      int row = wm * 16 + 4 * kq + i;
      partm[wn][row] = m4[i];
      partz[wn][row] = Zi[i];
      partp[wn][row] = Pi[i];
    }
  }
  __syncthreads();
  if (tid < 64) {
    float m0 = partm[0][tid], m1 = partm[1][tid];
    float m = fminf(m0, m1);
    float e0 = __expf(TAUc * (m - m0)), e1 = __expf(TAUc * (m - m1));
    int g = (r0 + tid) * 4 + gc;
    rowm[g] = m;
    rowz[g] = partz[0][tid] * e0 + partz[1][tid] * e1;
    rowp[g] = partp[0][tid] * e0 + partp[1][tid] * e1;
  }
}

// ---------- fin: combine 4 col-group partials per row -> loss --------------------
__global__ __launch_bounds__(1024) void k_fin(const float* __restrict__ rowm,
                                              const float* __restrict__ rowz,
                                              const float* __restrict__ rowp,
                                              float* __restrict__ out) {
  __shared__ float sl[16];
  __shared__ int sc[16];
  int tid = threadIdx.x;
  int lane = tid & 63, w = tid >> 6;
  float ls = 0.f; int lc = 0;
  for (int r = tid; r < NB; r += 1024) {
    float4 mv = ((const float4*)rowm)[r];
    float4 zv = ((const float4*)rowz)[r];
    float4 pv = ((const float4*)rowp)[r];
    float m = fminf(fminf(mv.x, mv.y), fminf(mv.z, mv.w));
    float e0 = __expf(TAUc * (m - mv.x));
    float e1 = __expf(TAUc * (m - mv.y));
    float e2 = __expf(TAUc * (m - mv.z));
    float e3 = __expf(TAUc * (m - mv.w));
    float Z = zv.x * e0 + zv.y * e1 + zv.z * e2 + zv.w * e3;
    float P = pv.x * e0 + pv.y * e1 + pv.z * e2 + pv.w * e3;
    float Ps = P / Z;
    if (Ps > 0.f) { ls += logf(Ps); ++lc; }
  }
  #pragma unroll
  for (int o = 1; o < 64; o <<= 1) { ls += __shfl_xor(ls, o, 64); lc += __shfl_xor(lc, o, 64); }
  if (lane == 0) { sl[w] = ls; sc[w] = lc; }
  __syncthreads();
  if (tid == 0) {
    float s = 0.f; int c = 0;
    #pragma unroll
    for (int i = 0; i < 16; ++i) { s += sl[i]; c += sc[i]; }
    out[0] = -s / fmaxf((float)c, 1.0f);
  }
}

extern "C" void kernel_launch(void* const* d_in, const int* in_sizes, int n_in,
                              void* d_out, int out_size, void* d_ws, size_t ws_size,
                              hipStream_t stream) {
  const float* X     = (const float*)d_in[0];
  const int*   T     = (const int*)d_in[1];
  const float* means = (const float*)d_in[2];
  const float* logv  = (const float*)d_in[3];
  float* out = (float*)d_out;
  char* ws = (char*)d_ws;

  float*  rowm = (float*) (ws);                  // 64 KB  [4096][4]
  float*  rowz = (float*) (ws + 65536);          // 64 KB
  float*  rowp = (float*) (ws + 131072);         // 64 KB
  int*    colnz= (int*)   (ws + 196608);         // 2 KB
  int*    pos  = (int*)   (ws + 198656);         // 2 KB

  int Csel = (out_size - 1) / NB;
  int ident = (Csel == NC);   // Csel==NC forces all-ones mask (pos = identity)

  if (!ident) {
    k_zero<<<1, NC, 0, stream>>>(colnz);
    k_mask<<<NB / 16, 256, 0, stream>>>(T, colnz);
    k_scan<<<1, NC, 0, stream>>>(colnz, pos);
  }
  k_fused<<<256, 512, 0, stream>>>(X, T, means, logv, colnz, pos,
                                   out + 1, rowm, rowz, rowp, Csel, ident);
  k_fin<<<1, 1024, 0, stream>>>(rowm, rowz, rowp, out);
}